// Round 3
// baseline (1205.475 us; speedup 1.0000x reference)
//
#include <hip/hip_runtime.h>
#include <hip/hip_bf16.h>

// TimeLSTM fused persistent kernel for MI355X (gfx950), v3.
// B=2048, T=512, D=24, H=100, O=2. One block = 8 batch rows, all 512 steps.
// Re-tiled stationary weights: wave w<7 owns j-columns [16w,16w+16) with
// FIVE 16x16 output tiles {f,i,o,c~,decay} -> the whole gate quintet for a
// (row, j) lands in one lane's accumulators. Epilogue is register-local:
// no preact LDS round-trip, ONE barrier per step. Wave 7 stages x[s+1]/ts[s+1].

typedef __attribute__((ext_vector_type(8))) short bf16x8;
typedef __attribute__((ext_vector_type(4))) float f32x4;

#define B_SZ 2048
#define T_SZ 512
#define D_SZ 24
#define H_SZ 100
#define O_SZ 2

__device__ __forceinline__ unsigned short f2bf(float v) {
    return __builtin_bit_cast(unsigned short, __float2bfloat16(v));
}
__device__ __forceinline__ float sigm(float x) { return 1.0f / (1.0f + __expf(-x)); }
__device__ __forceinline__ float tanh_(float x) { return 2.0f / (1.0f + __expf(-2.0f * x)) - 1.0f; }

__global__ __launch_bounds__(512, 2) void tlstm_kernel(
    const float* __restrict__ input_seq, const float* __restrict__ ts,
    const float* __restrict__ W_all, const float* __restrict__ b_all,
    const float* __restrict__ U_all, const float* __restrict__ b_u,
    const float* __restrict__ W_d,  const float* __restrict__ b_d,
    const float* __restrict__ W_lin, const float* __restrict__ b_lin,
    float* __restrict__ out)
{
    // hx/cx: [parity][16 rows][128 k-slots] bf16, XOR-swizzled per row:
    //   idx = r*128 + (k ^ ((r&7)<<3));  slots 0..99 h (resp. c), 100..123 x
    //   (resp. 0), 124 = 1.0 bias row, 125..127 = 0.  Rows 8..15 stay zero.
    __shared__ unsigned short hx[2][16 * 128];
    __shared__ unsigned short cx[2][16 * 128];
    __shared__ float ts_lds[2][8];
    __shared__ float hl[8][H_SZ];   // final h (f32) for the output head

    const int tid   = (int)threadIdx.x;
    const int lane  = tid & 63;
    const int wave  = tid >> 6;
    const int row16 = lane & 15;
    const int kgrp  = lane >> 4;
    const int rowbase = (int)blockIdx.x * 8;

    // ---- init both parities: zeros + bias slot (k=124) = 1.0 for rows 0..7 ----
    for (int i = tid; i < 2 * 16 * 128; i += 512) {
        const int p = i >> 11, r = (i >> 7) & 15, k = i & 127;
        const unsigned short v = (r < 8 && k == 124) ? (unsigned short)0x3F80 : (unsigned short)0;
        const int idx = r * 128 + (k ^ ((r & 7) << 3));
        hx[p][idx] = v;
        cx[p][idx] = v;
    }

    // ---- stationary B fragments: wave w<7 -> j in [16w,16w+16), 5 tiles ----
    // tile t<4: gate chunk t (W_all col t*100+j, U_all rows 100..123, bias 124)
    // tile t=4: decay (W_d col j, bias 124). jj>=100 (incl. all of wave 7) -> zeros.
    const int jj = wave * 16 + row16;
    bf16x8 Bf[5][4];
    #pragma unroll
    for (int t = 0; t < 5; ++t) {
        #pragma unroll
        for (int g = 0; g < 4; ++g) {
            bf16x8 fr;
            #pragma unroll
            for (int e = 0; e < 8; ++e) {
                const int k = g * 32 + kgrp * 8 + e;
                float v = 0.0f;
                if (jj < H_SZ) {
                    if (t < 4) {
                        const int n = t * H_SZ + jj;
                        if (k < 100)       v = W_all[k * 400 + n];
                        else if (k < 124)  v = U_all[(k - 100) * 400 + n];
                        else if (k == 124) v = b_all[n] + b_u[n];
                    } else {
                        if (k < 100)       v = W_d[k * 100 + jj];
                        else if (k == 124) v = b_d[jj];
                    }
                }
                fr[e] = (short)f2bf(v);
            }
            Bf[t][g] = fr;
        }
    }

    __syncthreads();   // init visible before staging overwrites x slots

    // ---- stage x[0] and ts[0] into parity 0 (wave 7 = staging wave) ----
    if (wave == 7) {
        #pragma unroll
        for (int q = 0; q < 3; ++q) {
            const int ii = lane * 3 + q;            // 0..191
            const int r = ii / 24, d = ii % 24;
            const float v = input_seq[((size_t)(rowbase + r) * T_SZ + 0) * D_SZ + d];
            hx[0][r * 128 + ((100 + d) ^ ((r & 7) << 3))] = f2bf(v);
        }
        if (lane < 8) ts_lds[0][lane] = ts[(size_t)(rowbase + lane) * T_SZ + 0];
    }

    bf16x8 zfr;
    #pragma unroll
    for (int e = 0; e < 8; ++e) zfr[e] = 0;

    const int rb = (lane >> 4) * 4;                 // epilogue row base (lanes<32)
    const bool epi = (wave < 7) && (lane < 32) && (jj < H_SZ);
    float cst[4] = {0.f, 0.f, 0.f, 0.f};            // f32 cell state carry

    __syncthreads();

    int par = 0;
    for (int s = 0; s < T_SZ; ++s) {
        const unsigned short* hp = hx[par];
        const unsigned short* cp = cx[par];

        bf16x8 ah[4], ac[4];
        f32x4 acc[5];
        if (wave < 7) {
            // A-frags; rows 8..15 are zero -> masked read (half-wave LDS traffic)
            #pragma unroll
            for (int g = 0; g < 4; ++g) {
                if (row16 < 8) {
                    const int idx = row16 * 128 + ((g * 32 + kgrp * 8) ^ ((row16 & 7) << 3));
                    ah[g] = *(const bf16x8*)(hp + idx);
                    ac[g] = *(const bf16x8*)(cp + idx);
                } else { ah[g] = zfr; ac[g] = zfr; }
            }
            #pragma unroll
            for (int t = 0; t < 4; ++t) {
                f32x4 a = {0.f, 0.f, 0.f, 0.f};
                #pragma unroll
                for (int g = 0; g < 4; ++g)
                    a = __builtin_amdgcn_mfma_f32_16x16x32_bf16(ah[g], Bf[t][g], a, 0, 0, 0);
                acc[t] = a;
            }
            {
                f32x4 a = {0.f, 0.f, 0.f, 0.f};
                #pragma unroll
                for (int g = 0; g < 4; ++g)
                    a = __builtin_amdgcn_mfma_f32_16x16x32_bf16(ac[g], Bf[4][g], a, 0, 0, 0);
                acc[4] = a;
            }
        } else {
            // staging wave: x[s+1], ts[s+1] into the other parity (hidden under MFMA)
            const int s1 = (s + 1 < T_SZ) ? (s + 1) : s;
            #pragma unroll
            for (int q = 0; q < 3; ++q) {
                const int ii = lane * 3 + q;
                const int r = ii / 24, d = ii % 24;
                const float v = input_seq[((size_t)(rowbase + r) * T_SZ + s1) * D_SZ + d];
                hx[par ^ 1][r * 128 + ((100 + d) ^ ((r & 7) << 3))] = f2bf(v);
            }
            if (lane < 8) ts_lds[par ^ 1][lane] = ts[(size_t)(rowbase + lane) * T_SZ + s1];
        }

        // register-local epilogue: lane owns (rows rb..rb+3, col jj), all 5 preacts
        if (epi) {
            unsigned short* hn = hx[par ^ 1];
            unsigned short* cn = cx[par ^ 1];
            #pragma unroll
            for (int e = 0; e < 4; ++e) {
                const int r = rb + e;
                const float tsv = ts_lds[par][r];
                const float f = sigm(acc[0][e]);
                const float i = sigm(acc[1][e]);
                const float o = sigm(acc[2][e]);
                const float g = sigm(acc[3][e]);
                const float cs = tanh_(acc[4][e]);
                const float ca = cst[e] + cs * (tsv - 1.0f);   // (c - cs) + cs*t
                cst[e] = f * ca + i * g;
                const float h = o * tanh_(cst[e]);
                const int ix = r * 128 + (jj ^ ((r & 7) << 3));
                hn[ix] = f2bf(h);
                cn[ix] = f2bf(cst[e]);
                if (s == T_SZ - 1) hl[r][jj] = h;
            }
        }

        __syncthreads();   // single barrier per step (double-buffered state)
        par ^= 1;
    }

    // ---- output head: relu(h_last @ W_lin + b_lin), parallel reduce ----
    {
        const int r  = tid >> 6;        // 0..7 (one wave per row)
        const int o  = (tid >> 5) & 1;  // half-wave per output col
        const int k0 = tid & 31;
        float part = 0.f;
        for (int k = k0; k < H_SZ; k += 32)
            part += hl[r][k] * W_lin[k * O_SZ + o];
        #pragma unroll
        for (int off = 16; off; off >>= 1)
            part += __shfl_xor(part, off, 64);
        if (k0 == 0)
            out[(size_t)(rowbase + r) * O_SZ + o] = fmaxf(part + b_lin[o], 0.f);
    }
}

extern "C" void kernel_launch(void* const* d_in, const int* in_sizes, int n_in,
                              void* d_out, int out_size, void* d_ws, size_t ws_size,
                              hipStream_t stream) {
    const float* input_seq = (const float*)d_in[0];
    const float* ts_p      = (const float*)d_in[1];
    const float* W_all     = (const float*)d_in[2];
    const float* b_all     = (const float*)d_in[3];
    const float* U_all     = (const float*)d_in[4];
    const float* b_u       = (const float*)d_in[5];
    const float* W_d       = (const float*)d_in[6];
    const float* b_d       = (const float*)d_in[7];
    const float* W_lin     = (const float*)d_in[8];
    const float* b_lin     = (const float*)d_in[9];

    tlstm_kernel<<<dim3(B_SZ / 8), dim3(512), 0, stream>>>(
        input_seq, ts_p, W_all, b_all, U_all, b_u, W_d, b_d, W_lin, b_lin,
        (float*)d_out);
}

// Round 4
// 623.210 us; speedup vs baseline: 1.9343x; 1.9343x over previous
//
#include <hip/hip_runtime.h>
#include <hip/hip_bf16.h>

// TimeLSTM fused persistent kernel for MI355X (gfx950), v4.
// B=2048, T=512, D=24, H=100, O=2. One block = 8 batch rows, all 512 steps.
// Wave w<7 owns j-columns [16w,16w+16) with FIVE 16x16 output tiles
// {f,i,o,c~,decay}; gate quintet lands in lane accumulators. v4: fast
// exp2/rcp transcendentals (no IEEE div), epilogue spread over all 64 lanes
// via shfl_xor(32), unconditional full-wave A-frag reads (rows 8..15 are
// zeros in LDS). One barrier per step. Wave 7 stages x[s+1]/ts[s+1].

typedef __attribute__((ext_vector_type(8))) short bf16x8;
typedef __attribute__((ext_vector_type(4))) float f32x4;

#define B_SZ 2048
#define T_SZ 512
#define D_SZ 24
#define H_SZ 100
#define O_SZ 2

__device__ __forceinline__ unsigned short f2bf(float v) {
    return __builtin_bit_cast(unsigned short, __float2bfloat16(v));
}
__device__ __forceinline__ float fexp2(float x) { return __builtin_amdgcn_exp2f(x); }
__device__ __forceinline__ float frcp (float x) { return __builtin_amdgcn_rcpf(x); }
// sigmoid(x) = 1/(1+2^(-x*log2e))            : ~4 VALU
__device__ __forceinline__ float sigm(float x) { return frcp(1.0f + fexp2(-1.44269504f * x)); }
// tanh(x) = 1 - 2/(1+2^(2x*log2e))           : ~5 VALU
__device__ __forceinline__ float tanh_(float x) {
    return __builtin_fmaf(-2.0f, frcp(1.0f + fexp2(2.88539008f * x)), 1.0f);
}

__global__ __launch_bounds__(512, 2) void tlstm_kernel(
    const float* __restrict__ input_seq, const float* __restrict__ ts,
    const float* __restrict__ W_all, const float* __restrict__ b_all,
    const float* __restrict__ U_all, const float* __restrict__ b_u,
    const float* __restrict__ W_d,  const float* __restrict__ b_d,
    const float* __restrict__ W_lin, const float* __restrict__ b_lin,
    float* __restrict__ out)
{
    // hx/cx: [parity][16 rows][128 k-slots] bf16, XOR-swizzled per row:
    //   idx = r*128 + (k ^ ((r&7)<<3));  slots 0..99 h (resp. c), 100..123 x
    //   (resp. 0), 124 = 1.0 bias row, 125..127 = 0.  Rows 8..15 stay zero.
    __shared__ unsigned short hx[2][16 * 128];
    __shared__ unsigned short cx[2][16 * 128];
    __shared__ float ts_lds[2][8];
    __shared__ float hl[8][H_SZ];   // final h (f32) for the output head

    const int tid   = (int)threadIdx.x;
    const int lane  = tid & 63;
    const int wave  = tid >> 6;
    const int row16 = lane & 15;
    const int kgrp  = lane >> 4;
    const int rowbase = (int)blockIdx.x * 8;

    // ---- init both parities: zeros + bias slot (k=124) = 1.0 for rows 0..7 ----
    for (int i = tid; i < 2 * 16 * 128; i += 512) {
        const int p = i >> 11, r = (i >> 7) & 15, k = i & 127;
        const unsigned short v = (r < 8 && k == 124) ? (unsigned short)0x3F80 : (unsigned short)0;
        const int idx = r * 128 + (k ^ ((r & 7) << 3));
        hx[p][idx] = v;
        cx[p][idx] = v;
    }

    // ---- stationary B fragments: wave w<7 -> j in [16w,16w+16), 5 tiles ----
    const int jj = wave * 16 + row16;
    bf16x8 Bf[5][4];
    #pragma unroll
    for (int t = 0; t < 5; ++t) {
        #pragma unroll
        for (int g = 0; g < 4; ++g) {
            bf16x8 fr;
            #pragma unroll
            for (int e = 0; e < 8; ++e) {
                const int k = g * 32 + kgrp * 8 + e;
                float v = 0.0f;
                if (jj < H_SZ) {
                    if (t < 4) {
                        const int n = t * H_SZ + jj;
                        if (k < 100)       v = W_all[k * 400 + n];
                        else if (k < 124)  v = U_all[(k - 100) * 400 + n];
                        else if (k == 124) v = b_all[n] + b_u[n];
                    } else {
                        if (k < 100)       v = W_d[k * 100 + jj];
                        else if (k == 124) v = b_d[jj];
                    }
                }
                fr[e] = (short)f2bf(v);
            }
            Bf[t][g] = fr;
        }
    }

    __syncthreads();   // init visible before staging overwrites x slots

    // ---- stage x[0] and ts[0] into parity 0 (wave 7 = staging wave) ----
    if (wave == 7) {
        #pragma unroll
        for (int q = 0; q < 3; ++q) {
            const int ii = lane * 3 + q;            // 0..191
            const int r = ii / 24, d = ii % 24;
            const float v = input_seq[((size_t)(rowbase + r) * T_SZ + 0) * D_SZ + d];
            hx[0][r * 128 + ((100 + d) ^ ((r & 7) << 3))] = f2bf(v);
        }
        if (lane < 8) ts_lds[0][lane] = ts[(size_t)(rowbase + lane) * T_SZ + 0];
    }

    const bool hi  = (lane >= 32);
    const int  rb2 = (((lane & 31) >> 4) << 2) + (hi ? 2 : 0);  // this lane's 2 rows: rb2, rb2+1
    const bool epi = (wave < 7) && (jj < H_SZ);
    float cst[2] = {0.f, 0.f};                       // f32 cell-state carry (2 rows)

    __syncthreads();

    int par = 0;
    for (int s = 0; s < T_SZ; ++s) {
        const unsigned short* hp = hx[par];
        const unsigned short* cp = cx[par];

        if (wave < 7) {
            // full-wave A-frag reads (rows 8..15 read zeros; no branch, no cndmask)
            bf16x8 ah[4], ac[4];
            #pragma unroll
            for (int g = 0; g < 4; ++g) {
                const int idx = row16 * 128 + ((g * 32 + kgrp * 8) ^ ((row16 & 7) << 3));
                ah[g] = *(const bf16x8*)(hp + idx);
                ac[g] = *(const bf16x8*)(cp + idx);
            }

            f32x4 acc[5];
            #pragma unroll
            for (int t = 0; t < 4; ++t) {
                f32x4 a = {0.f, 0.f, 0.f, 0.f};
                #pragma unroll
                for (int g = 0; g < 4; ++g)
                    a = __builtin_amdgcn_mfma_f32_16x16x32_bf16(ah[g], Bf[t][g], a, 0, 0, 0);
                acc[t] = a;
            }
            {
                f32x4 a = {0.f, 0.f, 0.f, 0.f};
                #pragma unroll
                for (int g = 0; g < 4; ++g)
                    a = __builtin_amdgcn_mfma_f32_16x16x32_bf16(ac[g], Bf[4][g], a, 0, 0, 0);
                acc[4] = a;
            }

            // redistribute: lanes>=32 take elems {2,3} of paired low lane
            // (all 64 lanes participate in shfl; selection after)
            float p[2][5];
            #pragma unroll
            for (int t = 0; t < 5; ++t) {
                const float s2 = __shfl_xor(acc[t][2], 32, 64);
                const float s3 = __shfl_xor(acc[t][3], 32, 64);
                p[0][t] = hi ? s2 : acc[t][0];
                p[1][t] = hi ? s3 : acc[t][1];
            }

            if (epi) {
                unsigned short* hn = hx[par ^ 1];
                unsigned short* cn = cx[par ^ 1];
                #pragma unroll
                for (int e = 0; e < 2; ++e) {
                    const int r = rb2 + e;
                    const float tsv = ts_lds[par][r];
                    const float f = sigm(p[e][0]);
                    const float i = sigm(p[e][1]);
                    const float o = sigm(p[e][2]);
                    const float g = sigm(p[e][3]);
                    const float cs = tanh_(p[e][4]);
                    const float ca = cst[e] + cs * (tsv - 1.0f);   // (c - cs) + cs*t
                    cst[e] = f * ca + i * g;
                    const float h = o * tanh_(cst[e]);
                    const int ix = r * 128 + (jj ^ ((r & 7) << 3));
                    hn[ix] = f2bf(h);
                    cn[ix] = f2bf(cst[e]);
                    if (s == T_SZ - 1) hl[r][jj] = h;
                }
            }
        } else {
            // staging wave: x[s+1], ts[s+1] into the other parity (hidden under MFMA)
            const int s1 = (s + 1 < T_SZ) ? (s + 1) : s;
            #pragma unroll
            for (int q = 0; q < 3; ++q) {
                const int ii = lane * 3 + q;
                const int r = ii / 24, d = ii % 24;
                const float v = input_seq[((size_t)(rowbase + r) * T_SZ + s1) * D_SZ + d];
                hx[par ^ 1][r * 128 + ((100 + d) ^ ((r & 7) << 3))] = f2bf(v);
            }
            if (lane < 8) ts_lds[par ^ 1][lane] = ts[(size_t)(rowbase + lane) * T_SZ + s1];
        }

        __syncthreads();   // single barrier per step (double-buffered state)
        par ^= 1;
    }

    // ---- output head: relu(h_last @ W_lin + b_lin), parallel reduce ----
    {
        const int r  = tid >> 6;        // 0..7 (one wave per row)
        const int o  = (tid >> 5) & 1;  // half-wave per output col
        const int k0 = tid & 31;
        float part = 0.f;
        for (int k = k0; k < H_SZ; k += 32)
            part += hl[r][k] * W_lin[k * O_SZ + o];
        #pragma unroll
        for (int off = 16; off; off >>= 1)
            part += __shfl_xor(part, off, 64);
        if (k0 == 0)
            out[(size_t)(rowbase + r) * O_SZ + o] = fmaxf(part + b_lin[o], 0.f);
    }
}

extern "C" void kernel_launch(void* const* d_in, const int* in_sizes, int n_in,
                              void* d_out, int out_size, void* d_ws, size_t ws_size,
                              hipStream_t stream) {
    const float* input_seq = (const float*)d_in[0];
    const float* ts_p      = (const float*)d_in[1];
    const float* W_all     = (const float*)d_in[2];
    const float* b_all     = (const float*)d_in[3];
    const float* U_all     = (const float*)d_in[4];
    const float* b_u       = (const float*)d_in[5];
    const float* W_d       = (const float*)d_in[6];
    const float* b_d       = (const float*)d_in[7];
    const float* W_lin     = (const float*)d_in[8];
    const float* b_lin     = (const float*)d_in[9];

    tlstm_kernel<<<dim3(B_SZ / 8), dim3(512), 0, stream>>>(
        input_seq, ts_p, W_all, b_all, U_all, b_u, W_d, b_d, W_lin, b_lin,
        (float*)d_out);
}